// Round 3
// baseline (328.773 us; speedup 1.0000x reference)
//
#include <hip/hip_runtime.h>
#include <hip/hip_bf16.h>

typedef __bf16 bf16;
typedef __bf16 bf16x8 __attribute__((ext_vector_type(8)));
typedef float  f32x4  __attribute__((ext_vector_type(4)));

// ---------------------------------------------------------------------------
// NNConv restructure:
//   msg[e] = Z[e] @ W' + d[src],  Z[e][(j,i)] = he[e][j]*x[src][i]
// The d[src] bias-contraction (d[s][o] = sum_i x[s][i]*b_b[i*16+o]) is folded
// into ONE extra quad-masked MFMA per tile (the lane already holds x[s]) --
// no random d-gather, no shfl(s) chain in the epilogue.
// Pooling: batch sorted -> per-graph block segment reduction, no atomics.
// ---------------------------------------------------------------------------

// Per-node: r1 = x@root1 + bias1
__global__ void node_pre1(const float* __restrict__ x,
                          const float* __restrict__ root1,
                          const float* __restrict__ bias1,
                          float* __restrict__ r1, int N)
{
    int t = blockIdx.x * blockDim.x + threadIdx.x;
    int v = t >> 4, o = t & 15;
    if (v >= N) return;
    float racc = 0.f;
#pragma unroll
    for (int i = 0; i < 8; ++i)
        racc += x[v * 8 + i] * root1[i * 16 + o];
    r1[v * 16 + o] = racc + bias1[o];
}

// Edge layer 1: 16 edges/wave-tile, K=128 via 4x mfma + 1 bias-mfma.
__global__ void __launch_bounds__(256, 8)
edge_l1(const float* __restrict__ x,
        const float* __restrict__ ea,
        const int*   __restrict__ eidx,
        const float* __restrict__ W_e1a, const float* __restrict__ b_e1a,
        const float* __restrict__ W_e1b, const float* __restrict__ b_e1b,
        float* __restrict__ agg, int* __restrict__ cnt,
        int E, int ntiles)
{
    const int lane = threadIdx.x & 63;
    const int m = lane & 15;          // A row (edge in tile) / B,C col (chan)
    const int q = lane >> 4;          // quad
    const int wave   = blockIdx.x * (blockDim.x >> 6) + (threadIdx.x >> 6);
    const int nwaves = gridDim.x * (blockDim.x >> 6);

    // B fragments: B[k][n] = W_e1b[(i*16+n)*16 + j], k=(j=c*4+q, i=t)
    bf16x8 bfrag[4];
#pragma unroll
    for (int c = 0; c < 4; ++c)
#pragma unroll
        for (int t = 0; t < 8; ++t)
            bfrag[c][t] = (bf16)W_e1b[(t * 16 + m) * 16 + (c * 4 + q)];
    // Bias MFMA B: k=q*8+t -> i (only quad 0 active, i=t<8)
    bf16x8 bfrag5 = {};
    if (q == 0)
#pragma unroll
        for (int t = 0; t < 8; ++t)
            bfrag5[t] = (bf16)b_e1b[t * 16 + m];

    for (int tile = wave; tile < ntiles; tile += nwaves) {
        int e = tile * 16 + m;
        int s = eidx[e];
        int d = eidx[E + e];
        float t_ea = ea[e];

        float he[4];
#pragma unroll
        for (int c = 0; c < 4; ++c) {
            int j = c * 4 + q;
            float h = W_e1a[j] * t_ea + b_e1a[j];
            he[c] = h > 0.f ? h : 0.f;
        }

        const float4* xp = (const float4*)(x + (size_t)s * 8);
        float4 x0 = xp[0], x1 = xp[1];
        float xv[8] = {x0.x, x0.y, x0.z, x0.w, x1.x, x1.y, x1.z, x1.w};

        f32x4 acc = {0.f, 0.f, 0.f, 0.f};
#pragma unroll
        for (int c = 0; c < 4; ++c) {
            bf16x8 afrag;
#pragma unroll
            for (int t = 0; t < 8; ++t) afrag[t] = (bf16)(he[c] * xv[t]);
            acc = __builtin_amdgcn_mfma_f32_16x16x32_bf16(afrag, bfrag[c], acc, 0, 0, 0);
        }
        // bias contraction: A5[m][k=q*8+t] = x[t] on quad 0
        {
            bf16x8 a5 = {};
            if (q == 0)
#pragma unroll
                for (int t = 0; t < 8; ++t) a5[t] = (bf16)xv[t];
            acc = __builtin_amdgcn_mfma_f32_16x16x32_bf16(a5, bfrag5, acc, 0, 0, 0);
        }

        if (q == 0) atomicAdd(&cnt[d], 1);

        // C layout: lane holds rows r=q*4+reg (edges), col m
#pragma unroll
        for (int reg = 0; reg < 4; ++reg) {
            int d_r = __shfl(d, q * 4 + reg, 64);
            atomicAdd(&agg[d_r * 16 + m], acc[reg]);
        }
    }
}

// Finalize layer 1 + r2 precompute.
__global__ void node_fin1(const float* __restrict__ agg, const int* __restrict__ cnt,
                          const float* __restrict__ r1,
                          const float* __restrict__ root2,
                          const float* __restrict__ bias2,
                          float* __restrict__ h1, float* __restrict__ r2, int N)
{
    int t = blockIdx.x * blockDim.x + threadIdx.x;
    int v = t >> 4, o = t & 15;
    if (v >= N) return;
    float c = (float)cnt[v]; c = c > 1.f ? c : 1.f;
    float h = agg[v * 16 + o] / c + r1[v * 16 + o];
    h = h > 0.f ? h : 0.f;
    h1[v * 16 + o] = h;
    float racc = 0.f;
#pragma unroll
    for (int i = 0; i < 16; ++i)
        racc += __shfl(h, i, 16) * root2[i * 16 + o];
    r2[v * 16 + o] = racc + bias2[o];
}

// Edge layer 2: K=256 via 8x mfma + 1 bias-mfma.
__global__ void __launch_bounds__(256, 8)
edge_l2(const float* __restrict__ h1g,
        const float* __restrict__ ea,
        const int*   __restrict__ eidx,
        const float* __restrict__ W_e2a, const float* __restrict__ b_e2a,
        const float* __restrict__ W_e2b, const float* __restrict__ b_e2b,
        float* __restrict__ agg, int E, int ntiles)
{
    const int lane = threadIdx.x & 63;
    const int m = lane & 15;
    const int q = lane >> 4;
    const int qh = q >> 1;            // j = 2c + qh
    const int ql = q & 1;             // i = ql*8 + t
    const int wave   = blockIdx.x * (blockDim.x >> 6) + (threadIdx.x >> 6);
    const int nwaves = gridDim.x * (blockDim.x >> 6);

    bf16x8 bfrag[8];
#pragma unroll
    for (int c = 0; c < 8; ++c) {
        int j = c * 2 + qh;
#pragma unroll
        for (int t = 0; t < 8; ++t)
            bfrag[c][t] = (bf16)W_e2b[((ql * 8 + t) * 16 + m) * 16 + j];
    }
    // Bias MFMA B: k=q*8+t -> i (quads 0,1 active: i = q*8+t)
    bf16x8 bfrag5 = {};
    if (q < 2)
#pragma unroll
        for (int t = 0; t < 8; ++t)
            bfrag5[t] = (bf16)b_e2b[(q * 8 + t) * 16 + m];

    for (int tile = wave; tile < ntiles; tile += nwaves) {
        int e = tile * 16 + m;
        int s = eidx[e];
        int d = eidx[E + e];
        float t_ea = ea[e];

        float he[8];
#pragma unroll
        for (int c = 0; c < 8; ++c) {
            int j = c * 2 + qh;
            float h = W_e2a[j] * t_ea + b_e2a[j];
            he[c] = h > 0.f ? h : 0.f;
        }

        const float4* hp = (const float4*)(h1g + (size_t)s * 16 + ql * 8);
        float4 h0 = hp[0], h1v = hp[1];
        float hv[8] = {h0.x, h0.y, h0.z, h0.w, h1v.x, h1v.y, h1v.z, h1v.w};

        f32x4 acc = {0.f, 0.f, 0.f, 0.f};
#pragma unroll
        for (int c = 0; c < 8; ++c) {
            bf16x8 afrag;
#pragma unroll
            for (int t = 0; t < 8; ++t) afrag[t] = (bf16)(he[c] * hv[t]);
            acc = __builtin_amdgcn_mfma_f32_16x16x32_bf16(afrag, bfrag[c], acc, 0, 0, 0);
        }
        // bias contraction: lane already holds h1[s][q*8..q*8+8) on quads 0,1
        {
            bf16x8 a5 = {};
            if (q < 2)
#pragma unroll
                for (int t = 0; t < 8; ++t) a5[t] = (bf16)hv[t];
            acc = __builtin_amdgcn_mfma_f32_16x16x32_bf16(a5, bfrag5, acc, 0, 0, 0);
        }

#pragma unroll
        for (int reg = 0; reg < 4; ++reg) {
            int d_r = __shfl(d, q * 4 + reg, 64);
            atomicAdd(&agg[d_r * 16 + m], acc[reg]);
        }
    }
}

// Finalize layer 2: pure streaming elementwise.
__global__ void node_fin2(const float* __restrict__ agg, const int* __restrict__ cnt,
                          const float* __restrict__ r2, const int* __restrict__ batch,
                          float* __restrict__ out_h, float* __restrict__ out_b, int N)
{
    int t = blockIdx.x * blockDim.x + threadIdx.x;
    int v = t >> 4, o = t & 15;
    if (v >= N) return;
    float c = (float)cnt[v]; c = c > 1.f ? c : 1.f;
    float h = agg[v * 16 + o] / c + r2[v * 16 + o];
    h = h > 0.f ? h : 0.f;
    out_h[v * 16 + o] = h;
    if (o == 0) out_b[v] = (float)batch[v];
}

// Global mean pool: one block per graph, binary-search range, LDS reduce.
__global__ void pool_seg(const float* __restrict__ h, const int* __restrict__ batch,
                         float* __restrict__ out_g, int N)
{
    const int b = blockIdx.x;
    int lo = 0, hi = N;
    while (lo < hi) { int mid = (lo + hi) >> 1; if (batch[mid] < b) lo = mid + 1; else hi = mid; }
    const int start = lo;
    hi = N;
    while (lo < hi) { int mid = (lo + hi) >> 1; if (batch[mid] < b + 1) lo = mid + 1; else hi = mid; }
    const int end = lo;

    const int ch = threadIdx.x & 15, grp = threadIdx.x >> 4;
    float acc = 0.f;
    for (int v = start + grp; v < end; v += 16)
        acc += h[(size_t)v * 16 + ch];

    __shared__ float red[256];
    red[threadIdx.x] = acc;
    __syncthreads();
#pragma unroll
    for (int s = 128; s >= 16; s >>= 1) {
        if (threadIdx.x < s) red[threadIdx.x] += red[threadIdx.x + s];
        __syncthreads();
    }
    if (threadIdx.x < 16) {
        float c = (float)(end - start); c = c > 1.f ? c : 1.f;
        out_g[b * 16 + threadIdx.x] = red[threadIdx.x] / c;
    }
}

extern "C" void kernel_launch(void* const* d_in, const int* in_sizes, int n_in,
                              void* d_out, int out_size, void* d_ws, size_t ws_size,
                              hipStream_t stream)
{
    const float* x     = (const float*)d_in[0];
    const float* ea    = (const float*)d_in[1];
    const float* W_e1a = (const float*)d_in[2];
    const float* b_e1a = (const float*)d_in[3];
    const float* W_e1b = (const float*)d_in[4];
    const float* b_e1b = (const float*)d_in[5];
    const float* root1 = (const float*)d_in[6];
    const float* bias1 = (const float*)d_in[7];
    const float* W_e2a = (const float*)d_in[8];
    const float* b_e2a = (const float*)d_in[9];
    const float* W_e2b = (const float*)d_in[10];
    const float* b_e2b = (const float*)d_in[11];
    const float* root2 = (const float*)d_in[12];
    const float* bias2 = (const float*)d_in[13];
    const int*   eidx  = (const int*)d_in[14];
    const int*   batch = (const int*)d_in[15];

    const int E  = in_sizes[1];       // 800000
    const int N  = in_sizes[15];      // 50000
    const int Bg = (out_size - N * 16 - N) / 16;   // 64

    char* ws = (char*)d_ws;
    size_t off = 0;
    int*   cnt  = (int*)(ws + off);   off += (size_t)N * 4;
    float* agg1 = (float*)(ws + off); off += (size_t)N * 16 * 4;
    float* agg2 = (float*)(ws + off); off += (size_t)N * 16 * 4;
    size_t zero_bytes = off;
    float* h1 = (float*)(ws + off); off += (size_t)N * 16 * 4;
    float* r1 = (float*)(ws + off); off += (size_t)N * 16 * 4;
    float* r2 = (float*)(ws + off); off += (size_t)N * 16 * 4;

    hipMemsetAsync(d_ws, 0, zero_bytes, stream);

    int nodeBlocks = (N * 16 + 255) / 256;
    int ntiles = E / 16;

    node_pre1<<<nodeBlocks, 256, 0, stream>>>(x, root1, bias1, r1, N);
    edge_l1<<<2048, 256, 0, stream>>>(x, ea, eidx, W_e1a, b_e1a, W_e1b, b_e1b,
                                      agg1, cnt, E, ntiles);
    node_fin1<<<nodeBlocks, 256, 0, stream>>>(agg1, cnt, r1, root2, bias2,
                                              h1, r2, N);
    edge_l2<<<2048, 256, 0, stream>>>(h1, ea, eidx, W_e2a, b_e2a, W_e2b, b_e2b,
                                      agg2, E, ntiles);

    float* out_h = (float*)d_out;
    float* out_g = out_h + (size_t)N * 16;
    float* out_b = out_g + (size_t)Bg * 16;
    node_fin2<<<nodeBlocks, 256, 0, stream>>>(agg2, cnt, r2, batch, out_h,
                                              out_b, N);
    pool_seg<<<Bg, 256, 0, stream>>>(out_h, batch, out_g, N);
}